// Round 4
// baseline (234.962 us; speedup 1.0000x reference)
//
#include <hip/hip_runtime.h>
#include <stdint.h>

#define TT 512
#define BB 32
#define EE 512
#define HH 2048

typedef __attribute__((ext_vector_type(8))) short short8;   // 8 x bf16 (4 VGPRs)
typedef __attribute__((ext_vector_type(4))) float f32x4;    // MFMA accumulator

// LDS geometry (in shorts)
#define XROW 520            // 512 data + 8 pad (1040 B row stride: A-frag ds_read_b128
                            // pattern is exactly 8-phase conflict-free at this stride)
#define XBUF (16 * XROW)    // one 16-t chunk buffer = 8320 shorts
#define NBUF 3              // triple buffer (prefetch distance 2)

static __device__ __forceinline__ unsigned short f2bf(float f) {
    union { float f; unsigned u; } v; v.f = f;
    unsigned u = v.u;
    unsigned r = u + 0x7FFFu + ((u >> 16) & 1u);   // round-to-nearest-even
    return (unsigned short)(r >> 16);
}

static __device__ __forceinline__ float fast_exp(float x) {
    return __builtin_amdgcn_exp2f(x * 1.44269504f);
}
static __device__ __forceinline__ float fast_rcp(float x) {
    return __builtin_amdgcn_rcpf(x);
}

// Async global->LDS DMA, 16 B/lane (whole wave = 1 KB contiguous at uniform
// LDS base + lane*16). Integer detour for the address-space casts: AS1 keeps
// the full 64-bit VA; AS3 takes the low 32 bits (= LDS offset; shared-aperture
// base has zero low bits). This is the CK/AITER-standard pattern.
static __device__ __forceinline__ void load_lds16(const unsigned short* g, unsigned short* l) {
    __builtin_amdgcn_global_load_lds(
        (const __attribute__((address_space(1))) unsigned int*)(uintptr_t)g,
        (__attribute__((address_space(3))) unsigned int*)(uintptr_t)l,
        16, 0, 0);
}

// ---------------------------------------------------------------------------
// Pre-kernel: convert sent (T,B,E) fp32 and W (3H,E) fp32 to bf16 in ws.
// ---------------------------------------------------------------------------
__global__ void convert_inputs(const float* __restrict__ X,
                               const float* __restrict__ W,
                               unsigned short* __restrict__ Xb,
                               unsigned short* __restrict__ Wb) {
    const int nX = TT * BB * EE;              // 8,388,608 (divisible by 8)
    int i = (blockIdx.x * blockDim.x + threadIdx.x) * 8;
    const float* src;
    unsigned short* dst;
    int j;
    if (i < nX) { src = X; dst = Xb; j = i; }
    else        { src = W; dst = Wb; j = i - nX; }
    float4 v0 = *(const float4*)(src + j);
    float4 v1 = *(const float4*)(src + j + 4);
    union { short8 s; unsigned short u[8]; } o;
    o.u[0] = f2bf(v0.x); o.u[1] = f2bf(v0.y); o.u[2] = f2bf(v0.z); o.u[3] = f2bf(v0.w);
    o.u[4] = f2bf(v1.x); o.u[5] = f2bf(v1.y); o.u[6] = f2bf(v1.z); o.u[7] = f2bf(v1.w);
    *(short8*)(dst + j) = o.s;
}

// ---------------------------------------------------------------------------
// Fused QRNN kernel, pipelined K-split variant.
// Block = (batch b, 32 h-cols), 4 waves = 2 h-tiles x 2 k-halves.
// - W frags (96 regs/wave) pinned into AGPRs ("a" constraint): MFMA reads them
//   in place; kills the ~96 v_accvgpr_read/chunk/wave seen in R3.
// - X staged by global_load_lds into a 3-deep ring, prefetch distance 2.
// - ONE custom barrier per chunk: s_waitcnt vmcnt(4) lgkmcnt(0); s_barrier.
//   vmcnt(4) drains stage(n+1) (issued a full chunk ago) while keeping
//   stage(n+2) in flight — the fine-grained-vmcnt pipelining __syncthreads
//   (vmcnt(0) drain, R3's ~72% stall) cannot express.
// - exch double-buffered so the single barrier covers all exch hazards.
// ---------------------------------------------------------------------------
__launch_bounds__(256, 2)
__global__ void qrnn_fused(const unsigned short* __restrict__ Xb, // bf16 (T,B,E)
                           const unsigned short* __restrict__ Wb, // bf16 (3H,E)
                           const float* __restrict__ bias,        // (3H)
                           float* __restrict__ out)               // (B,H) fp32
{
    __shared__ unsigned short xlds[NBUF * XBUF];   // 49,920 B
    __shared__ float exch[2][2][64][12];           // 12,288 B (ping-pong partials)

    const int tid  = threadIdx.x;
    const int wv   = tid >> 6;         // wave 0..3
    const int lane = tid & 63;
    const int q    = lane >> 4;        // quad 0..3
    const int c    = lane & 15;        // column within 16x16 tile
    const int hi   = wv >> 1;          // h-tile 0..1
    const int s    = wv & 1;           // k-half 0..1
    const int b    = blockIdx.y;
    const int h    = blockIdx.x * 32 + hi * 16 + c;

    // ---- preload W fragments (this wave's K half); pin into AGPRs ----
    // B-frag layout for 16x16x32: lane holds n = lane&15 (= h), k = q*8 + j.
    short8 wz[8], wf[8], wo[8];
    {
        const unsigned short* wzr = Wb + (size_t)h * EE            + s * 256;
        const unsigned short* wfr = Wb + (size_t)(HH + h) * EE     + s * 256;
        const unsigned short* wor = Wb + (size_t)(2 * HH + h) * EE + s * 256;
#pragma unroll
        for (int k = 0; k < 8; ++k) {
            int e0 = k * 32 + q * 8;
            wz[k] = *(const short8*)(wzr + e0);
            wf[k] = *(const short8*)(wfr + e0);
            wo[k] = *(const short8*)(wor + e0);
        }
    }
#pragma unroll
    for (int k = 0; k < 8; ++k) {
        asm volatile("" : "+a"(wz[k]), "+a"(wf[k]), "+a"(wo[k]));
    }

    const float b0 = (s == 0) ? bias[h]          : 0.0f;
    const float b1 = (s == 0) ? bias[HH + h]     : 0.0f;
    const float b2 = (s == 0) ? bias[2 * HH + h] : 0.0f;

    float carry = 0.0f;
    float vmax  = -1e30f;

    // ---- staging: wave wv owns rows wv*4 .. wv*4+3 of each 16-t chunk ----
    const unsigned short* g0 = Xb + ((size_t)(wv * 4) * BB + b) * EE + lane * 8;
    unsigned short* l0 = &xlds[(wv * 4) * XROW];

    auto stage = [&](int n, int slot) {
        const unsigned short* g = g0 + (size_t)n * (16 * BB * EE);
        unsigned short* l = l0 + slot * XBUF;
#pragma unroll
        for (int i = 0; i < 4; ++i)
            load_lds16(g + (size_t)i * (BB * EE), l + i * XROW);
    };

    stage(0, 0);
    stage(1, 1);
    // drain stage(0) (keep stage(1)'s 4 loads in flight), publish, barrier
    asm volatile("s_waitcnt vmcnt(4) lgkmcnt(0)\n\ts_barrier" ::: "memory");

    int buf = 0;
    for (int ch = 0; ch < 32; ++ch) {
        if (ch < 30) stage(ch + 2, (buf + 2 >= 3) ? buf - 1 : buf + 2);

        // ---- partial GEMM over this wave's K half (A from LDS, B from AGPR) ----
        f32x4 az = {b0, b0, b0, b0};
        f32x4 af = {b1, b1, b1, b1};
        f32x4 ao = {b2, b2, b2, b2};
        const unsigned short* Abase = &xlds[buf * XBUF + c * XROW + s * 256 + q * 8];
#pragma unroll
        for (int k = 0; k < 8; ++k) {
            short8 a = *(const short8*)(Abase + k * 32);
            az = __builtin_amdgcn_mfma_f32_16x16x32_bf16(a, wz[k], az, 0, 0, 0);
            af = __builtin_amdgcn_mfma_f32_16x16x32_bf16(a, wf[k], af, 0, 0, 0);
            ao = __builtin_amdgcn_mfma_f32_16x16x32_bf16(a, wo[k], ao, 0, 0, 0);
        }

        // ---- s=1 publishes its partials into this chunk's exch buffer ----
        const int eb = ch & 1;
        if (s == 1) {
            float* e = &exch[eb][hi][lane][0];
            *(f32x4*)(e)     = az;
            *(f32x4*)(e + 4) = af;
            *(f32x4*)(e + 8) = ao;
        }

        // ---- THE barrier: drain stage(ch+1) + all LDS ops; keep stage(ch+2) ----
        if (ch < 30) {
            asm volatile("s_waitcnt vmcnt(4) lgkmcnt(0)\n\ts_barrier" ::: "memory");
        } else {
            asm volatile("s_waitcnt vmcnt(0) lgkmcnt(0)\n\ts_barrier" ::: "memory");
        }

        // ---- s=0 tail (overlaps s=1 waves charging into chunk ch+1) ----
        if (s == 0) {
            const float* e = &exch[eb][hi][lane][0];
            f32x4 pz = *(const f32x4*)(e);
            f32x4 pf = *(const f32x4*)(e + 4);
            f32x4 po = *(const f32x4*)(e + 8);
            az = az + pz; af = af + pf; ao = ao + po;

            float aa[4], mm[4], oo[4];
#pragma unroll
            for (int r = 0; r < 4; ++r) {
                float e2 = fast_exp(2.0f * az[r]);
                float z  = 1.0f - 2.0f * fast_rcp(e2 + 1.0f);  // tanh
                float f  = fast_rcp(1.0f + fast_exp(-af[r]));  // sigmoid
                float o  = fast_rcp(1.0f + fast_exp(-ao[r]));  // sigmoid
                aa[r] = f * z;
                mm[r] = 1.0f - f;
                oo[r] = o;
            }

            // affine scan: compose 4 steps, scan across quads
            float A = aa[0], M = mm[0];
#pragma unroll
            for (int r = 1; r < 4; ++r) { A = aa[r] + mm[r] * A; M = mm[r] * M; }

            float Ap = __shfl_up(A, 16, 64), Mp = __shfl_up(M, 16, 64);
            if (q >= 1) { A = A + M * Ap; M = M * Mp; }
            Ap = __shfl_up(A, 32, 64); Mp = __shfl_up(M, 32, 64);
            if (q >= 2) { A = A + M * Ap; M = M * Mp; }
            float Ae = __shfl_up(A, 16, 64), Me = __shfl_up(M, 16, 64);
            if (q == 0) { Ae = 0.0f; Me = 1.0f; }
            float cc = Ae + Me * carry;

#pragma unroll
            for (int r = 0; r < 4; ++r) {
                cc = aa[r] + mm[r] * cc;
                vmax = fmaxf(vmax, oo[r] * cc);
            }

            float cend = A + M * carry;
            carry = __shfl(cend, 48 + c, 64);
        }

        buf = (buf >= 2) ? 0 : buf + 1;
    }

    if (s == 0) {
        vmax = fmaxf(vmax, __shfl_xor(vmax, 16, 64));
        vmax = fmaxf(vmax, __shfl_xor(vmax, 32, 64));
        if (q == 0) out[(size_t)b * HH + h] = vmax;
    }
}

// ---------------------------------------------------------------------------
extern "C" void kernel_launch(void* const* d_in, const int* in_sizes, int n_in,
                              void* d_out, int out_size, void* d_ws, size_t ws_size,
                              hipStream_t stream) {
    const float* sent = (const float*)d_in[0];
    // d_in[1] = lengths (unused by the math)
    const float* W    = (const float*)d_in[2];
    const float* bias = (const float*)d_in[3];
    float* out        = (float*)d_out;

    const int nX = TT * BB * EE;        // 8,388,608
    const int nW = 3 * HH * EE;         // 3,145,728
    unsigned short* Xb = (unsigned short*)d_ws;
    unsigned short* Wb = Xb + nX;       // 16 MiB offset, 16B-aligned

    int totalVec = (nX + nW) / 8;       // 1,441,792 threads, exact cover
    convert_inputs<<<totalVec / 256, 256, 0, stream>>>(sent, W, Xb, Wb);

    dim3 grid(HH / 32, BB);             // (64, 32) = 2048 blocks
    qrnn_fused<<<grid, 256, 0, stream>>>(Xb, Wb, bias, out);
}

// Round 6
// 215.519 us; speedup vs baseline: 1.0902x; 1.0902x over previous
//
#include <hip/hip_runtime.h>
#include <stdint.h>

#define TT 512
#define BB 32
#define EE 512
#define HH 2048

typedef __attribute__((ext_vector_type(8))) short short8;   // 8 x bf16 (4 VGPRs)
typedef __attribute__((ext_vector_type(4))) float f32x4;    // MFMA accumulator

// LDS geometry (in shorts)
#define XROW 528            // 512 data + 16 pad: measured 0 bank conflicts (R1/R3);
                            // 520 gave 8.4M conflicts (R4). Row stride 1056 B = 16*66.
#define XBUF (16 * XROW)    // one 16-t chunk buffer = 8448 shorts (16.5 KB)

static __device__ __forceinline__ unsigned short f2bf(float f) {
    union { float f; unsigned u; } v; v.f = f;
    unsigned u = v.u;
    unsigned r = u + 0x7FFFu + ((u >> 16) & 1u);   // round-to-nearest-even
    return (unsigned short)(r >> 16);
}

static __device__ __forceinline__ float fast_exp(float x) {
    return __builtin_amdgcn_exp2f(x * 1.44269504f);
}
static __device__ __forceinline__ float fast_rcp(float x) {
    return __builtin_amdgcn_rcpf(x);
}

// Async global->LDS DMA, 16 B/lane (wave-uniform LDS base + lane*16).
// Verified correct in R4 (passed, absmax 0.0039).
static __device__ __forceinline__ void load_lds16(const unsigned short* g, unsigned short* l) {
    __builtin_amdgcn_global_load_lds(
        (const __attribute__((address_space(1))) unsigned int*)(uintptr_t)g,
        (__attribute__((address_space(3))) unsigned int*)(uintptr_t)l,
        16, 0, 0);
}

// ---------------------------------------------------------------------------
// Pre-kernel: convert sent (T,B,E) fp32 and W (3H,E) fp32 to bf16 in ws.
// ---------------------------------------------------------------------------
__global__ void convert_inputs(const float* __restrict__ X,
                               const float* __restrict__ W,
                               unsigned short* __restrict__ Xb,
                               unsigned short* __restrict__ Wb) {
    const int nX = TT * BB * EE;              // 8,388,608 (divisible by 8)
    int i = (blockIdx.x * blockDim.x + threadIdx.x) * 8;
    const float* src;
    unsigned short* dst;
    int j;
    if (i < nX) { src = X; dst = Xb; j = i; }
    else        { src = W; dst = Wb; j = i - nX; }
    float4 v0 = *(const float4*)(src + j);
    float4 v1 = *(const float4*)(src + j + 4);
    union { short8 s; unsigned short u[8]; } o;
    o.u[0] = f2bf(v0.x); o.u[1] = f2bf(v0.y); o.u[2] = f2bf(v0.z); o.u[3] = f2bf(v0.w);
    o.u[4] = f2bf(v1.x); o.u[5] = f2bf(v1.y); o.u[6] = f2bf(v1.z); o.u[7] = f2bf(v1.w);
    *(short8*)(dst + j) = o.s;
}

// ---------------------------------------------------------------------------
// Fused QRNN kernel, K-split, verified-pieces recombination.
// Block = (batch b, 32 h-cols), 4 waves = 2 h-tiles x 2 k-halves.
// - INTRINSIC MFMAs only (hazard-safe; R5's asm MFMA + volatile-nop guard was
//   reorderable -> corruption). W frags pinned "+a" (96 AGPR/wave), consumed
//   in place by the intrinsic (av operand class on gfx950).
// - A-frags PREFETCHED: all 8 ds_read_b128 issued back-to-back, then 24 MFMAs.
//   R3's 76-VGPR allocation serialized read->mfma per k (~900 cyc/chunk);
//   launch_bounds(256,2) gives 256 unified regs/wave, room for 8 frags in flight.
// - X staged by global_load_lds DMA (R4-verified), double-buffered, XROW=528.
// - ONE __syncthreads per chunk; exch ping-pong by ch&1. Hazards: (1) publish
//   vs tail-read: barrier(ch). (2) tail-read(ch) vs re-publish(ch+2):
//   barrier(ch+1). (3) X buf reread/rewrite: lgkm drained at barrier. (4)
//   stage(ch+1) DMA vs consume in ch+1: vmcnt drained at barrier(ch).
// ---------------------------------------------------------------------------
__launch_bounds__(256, 2)
__global__ void qrnn_fused(const unsigned short* __restrict__ Xb, // bf16 (T,B,E)
                           const unsigned short* __restrict__ Wb, // bf16 (3H,E)
                           const float* __restrict__ bias,        // (3H)
                           float* __restrict__ out)               // (B,H) fp32
{
    __shared__ unsigned short xlds[2 * XBUF];      // 33,792 B
    __shared__ float exch[2][2][64][12];           // 12,288 B  (total 46,080 B)

    const int tid  = threadIdx.x;
    const int wv   = tid >> 6;         // wave 0..3
    const int lane = tid & 63;
    const int q    = lane >> 4;        // quad 0..3
    const int c    = lane & 15;        // column within 16x16 tile
    const int hi   = wv >> 1;          // h-tile 0..1
    const int s    = wv & 1;           // k-half 0..1
    const int b    = blockIdx.y;
    const int h    = blockIdx.x * 32 + hi * 16 + c;

    // ---- preload W fragments (this wave's K half); pin into AGPRs ----
    // B-frag layout for 16x16x32: lane holds n = lane&15 (= h), k = q*8 + j.
    short8 wz[8], wf[8], wo[8];
    {
        const unsigned short* wzr = Wb + (size_t)h * EE            + s * 256;
        const unsigned short* wfr = Wb + (size_t)(HH + h) * EE     + s * 256;
        const unsigned short* wor = Wb + (size_t)(2 * HH + h) * EE + s * 256;
#pragma unroll
        for (int k = 0; k < 8; ++k) {
            int e0 = k * 32 + q * 8;
            wz[k] = *(const short8*)(wzr + e0);
            wf[k] = *(const short8*)(wfr + e0);
            wo[k] = *(const short8*)(wor + e0);
        }
    }
    // Liveness pin in AGPR class: loads happen once, stay resident (R3/R4
    // verified: no refetch, no spill).
#pragma unroll
    for (int k = 0; k < 8; ++k) {
        asm volatile("" : "+a"(wz[k]), "+a"(wf[k]), "+a"(wo[k]));
    }

    const float b0 = (s == 0) ? bias[h]          : 0.0f;
    const float b1 = (s == 0) ? bias[HH + h]     : 0.0f;
    const float b2 = (s == 0) ? bias[2 * HH + h] : 0.0f;

    float carry = 0.0f;
    float vmax  = -1e30f;

    // ---- staging: wave wv owns rows wv*4 .. wv*4+3 of each 16-t chunk ----
    const unsigned short* g0 = Xb + ((size_t)(wv * 4) * BB + b) * EE + lane * 8;
    unsigned short* l0 = &xlds[(wv * 4) * XROW];

    auto stage = [&](int n, int slot) {
        const unsigned short* g = g0 + (size_t)n * (16 * BB * EE);
        unsigned short* l = l0 + slot * XBUF;
#pragma unroll
        for (int i = 0; i < 4; ++i)
            load_lds16(g + (size_t)i * (BB * EE), l + i * XROW);
    };

    stage(0, 0);
    __syncthreads();

    for (int ch = 0; ch < 32; ++ch) {
        const int buf = ch & 1;
        if (ch < 31) stage(ch + 1, buf ^ 1);

        // ---- prefetch ALL A-frags for this chunk (8 back-to-back b128) ----
        // lane holds m = lane&15 (= t within chunk), k = q*8 + j
        const unsigned short* Abase = &xlds[buf * XBUF + c * XROW + s * 256 + q * 8];
        short8 a[8];
#pragma unroll
        for (int k = 0; k < 8; ++k)
            a[k] = *(const short8*)(Abase + k * 32);

        // ---- MFMA burst: 24 MFMAs, 3 independent accumulator chains ----
        f32x4 az = {b0, b0, b0, b0};
        f32x4 af = {b1, b1, b1, b1};
        f32x4 ao = {b2, b2, b2, b2};
#pragma unroll
        for (int k = 0; k < 8; ++k) {
            az = __builtin_amdgcn_mfma_f32_16x16x32_bf16(a[k], wz[k], az, 0, 0, 0);
            af = __builtin_amdgcn_mfma_f32_16x16x32_bf16(a[k], wf[k], af, 0, 0, 0);
            ao = __builtin_amdgcn_mfma_f32_16x16x32_bf16(a[k], wo[k], ao, 0, 0, 0);
        }

        // ---- s=1 publishes partials into this chunk's exch ping-pong slot ----
        const int eb = ch & 1;
        if (s == 1) {
            float* e = &exch[eb][hi][lane][0];
            *(f32x4*)(e)     = az;
            *(f32x4*)(e + 4) = af;
            *(f32x4*)(e + 8) = ao;
        }

        __syncthreads();   // the ONE barrier per chunk (see header comment)

        // ---- s=0 tail (overlaps the other resident block on this SIMD) ----
        if (s == 0) {
            const float* e = &exch[eb][hi][lane][0];
            f32x4 pz = *(const f32x4*)(e);
            f32x4 pf = *(const f32x4*)(e + 4);
            f32x4 po = *(const f32x4*)(e + 8);
            az = az + pz; af = af + pf; ao = ao + po;

            float aa[4], mm[4], oo[4];
#pragma unroll
            for (int r = 0; r < 4; ++r) {
                float e2 = fast_exp(2.0f * az[r]);
                float z  = 1.0f - 2.0f * fast_rcp(e2 + 1.0f);  // tanh
                float f  = fast_rcp(1.0f + fast_exp(-af[r]));  // sigmoid
                float o  = fast_rcp(1.0f + fast_exp(-ao[r]));  // sigmoid
                aa[r] = f * z;
                mm[r] = 1.0f - f;
                oo[r] = o;
            }

            // affine scan: compose 4 steps, scan across quads
            float A = aa[0], M = mm[0];
#pragma unroll
            for (int r = 1; r < 4; ++r) { A = aa[r] + mm[r] * A; M = mm[r] * M; }

            float Ap = __shfl_up(A, 16, 64), Mp = __shfl_up(M, 16, 64);
            if (q >= 1) { A = A + M * Ap; M = M * Mp; }
            Ap = __shfl_up(A, 32, 64); Mp = __shfl_up(M, 32, 64);
            if (q >= 2) { A = A + M * Ap; M = M * Mp; }
            float Ae = __shfl_up(A, 16, 64), Me = __shfl_up(M, 16, 64);
            if (q == 0) { Ae = 0.0f; Me = 1.0f; }
            float cc = Ae + Me * carry;

#pragma unroll
            for (int r = 0; r < 4; ++r) {
                cc = aa[r] + mm[r] * cc;
                vmax = fmaxf(vmax, oo[r] * cc);
            }

            float cend = A + M * carry;
            carry = __shfl(cend, 48 + c, 64);
        }
    }

    if (s == 0) {
        vmax = fmaxf(vmax, __shfl_xor(vmax, 16, 64));
        vmax = fmaxf(vmax, __shfl_xor(vmax, 32, 64));
        if (q == 0) out[(size_t)b * HH + h] = vmax;
    }
}

// ---------------------------------------------------------------------------
extern "C" void kernel_launch(void* const* d_in, const int* in_sizes, int n_in,
                              void* d_out, int out_size, void* d_ws, size_t ws_size,
                              hipStream_t stream) {
    const float* sent = (const float*)d_in[0];
    // d_in[1] = lengths (unused by the math)
    const float* W    = (const float*)d_in[2];
    const float* bias = (const float*)d_in[3];
    float* out        = (float*)d_out;

    const int nX = TT * BB * EE;        // 8,388,608
    const int nW = 3 * HH * EE;         // 3,145,728
    unsigned short* Xb = (unsigned short*)d_ws;
    unsigned short* Wb = Xb + nX;       // 16 MiB offset, 16B-aligned

    int totalVec = (nX + nW) / 8;       // 1,441,792 threads, exact cover
    convert_inputs<<<totalVec / 256, 256, 0, stream>>>(sent, W, Xb, Wb);

    dim3 grid(HH / 32, BB);             // (64, 32) = 2048 blocks
    qrnn_fused<<<grid, 256, 0, stream>>>(Xb, Wb, bias, out);
}